// Round 18
// baseline (811.831 us; speedup 1.0000x reference)
//
#include <hip/hip_runtime.h>

typedef float f32x4 __attribute__((ext_vector_type(4)));

#define T_STEPS 512
#define BATCH   64
#define NIN     512
#define H       1024
#define BH      (BATCH * H)   // 65536
#define SENTU   0x7F7F7F7Fu   // sentinel bit pattern (3.39e38f)

#define BM 128
#define BN 128
#define BK 16
#define LDSS 132

#define T1S   308             // head covers t < 308 (must be even)
#define M1T   (T1S / 2)       // 154 head m-tiles
#define NI2   ((256 - M1T) * 8)  // 816 tail work items
#define PERS  384             // persistent GEMM blocks (2/CU on XCDs 2..7)

// device-coherent agent-scope access (R14-proven; R16 lesson: never hand-roll)
__device__ __forceinline__ float ld_agent(const float* p) {
    return __hip_atomic_load(p, __ATOMIC_RELAXED, __HIP_MEMORY_SCOPE_AGENT);
}
__device__ __forceinline__ void st_agent(float* p, float v) {
    __hip_atomic_store(p, v, __ATOMIC_RELAXED, __HIP_MEMORY_SCOPE_AGENT);
}

// ---------------------------------------------------------------------------
// Kernel 1: transpose w_rec [j][h] -> wrecT [h][j]
// ---------------------------------------------------------------------------
__global__ void transpose1024(const float* __restrict__ in, float* __restrict__ out) {
    __shared__ float tile[32][33];
    const int tx = threadIdx.x, ty = threadIdx.y;
    const int xg = blockIdx.x * 32 + tx;
    const int ybase = blockIdx.y * 32;
#pragma unroll
    for (int r = 0; r < 32; r += 8)
        tile[ty + r][tx] = in[(size_t)(ybase + ty + r) * H + xg];
    __syncthreads();
    const int x2 = blockIdx.y * 32 + tx;
    const int y2base = blockIdx.x * 32;
#pragma unroll
    for (int r = 0; r < 32; r += 8)
        out[(size_t)(y2base + ty + r) * H + x2] = tile[tx][ty + r];
}

// ---------------------------------------------------------------------------
// Kernel 2: HEAD GEMM (t < T1S), R22-dbuf (proven ~0.19us/block), full machine.
// ---------------------------------------------------------------------------
__global__ __launch_bounds__(256) void gemm_head(const float* __restrict__ x,
                                                 const float* __restrict__ w,
                                                 float* __restrict__ cur) {
    __shared__ __align__(16) float As[BK][LDSS];
    __shared__ __align__(16) float Bs[BK][LDSS];
    const int tid = threadIdx.x;
    const int tx = tid & 15, ty = tid >> 4;
    const int tx4 = tx * 4, ty4 = ty * 4;
    const int m0 = blockIdx.y * BM;
    const int n0 = blockIdx.x * BN;

    float acc[8][8];
#pragma unroll
    for (int i = 0; i < 8; ++i)
#pragma unroll
        for (int j = 0; j < 8; ++j) acc[i][j] = 0.0f;

    const int ar = tid >> 2;
    const int akc = (tid & 3) * 4;

    float4 a0 = *reinterpret_cast<const float4*>(&x[(size_t)(m0 + ar) * NIN + akc]);
    float4 a1 = *reinterpret_cast<const float4*>(&x[(size_t)(m0 + ar + 64) * NIN + akc]);
    float4 b0 = *reinterpret_cast<const float4*>(&w[(size_t)(n0 + ar) * NIN + akc]);
    float4 b1 = *reinterpret_cast<const float4*>(&w[(size_t)(n0 + ar + 64) * NIN + akc]);

    for (int k0 = 0; k0 < NIN; k0 += BK) {
        __syncthreads();
        As[akc + 0][ar] = a0.x; As[akc + 1][ar] = a0.y; As[akc + 2][ar] = a0.z; As[akc + 3][ar] = a0.w;
        As[akc + 0][ar + 64] = a1.x; As[akc + 1][ar + 64] = a1.y; As[akc + 2][ar + 64] = a1.z; As[akc + 3][ar + 64] = a1.w;
        Bs[akc + 0][ar] = b0.x; Bs[akc + 1][ar] = b0.y; Bs[akc + 2][ar] = b0.z; Bs[akc + 3][ar] = b0.w;
        Bs[akc + 0][ar + 64] = b1.x; Bs[akc + 1][ar + 64] = b1.y; Bs[akc + 2][ar + 64] = b1.z; Bs[akc + 3][ar + 64] = b1.w;
        __syncthreads();

        const int kn = (k0 + BK < NIN) ? (k0 + BK) : 0;
        a0 = *reinterpret_cast<const float4*>(&x[(size_t)(m0 + ar) * NIN + kn + akc]);
        a1 = *reinterpret_cast<const float4*>(&x[(size_t)(m0 + ar + 64) * NIN + kn + akc]);
        b0 = *reinterpret_cast<const float4*>(&w[(size_t)(n0 + ar) * NIN + kn + akc]);
        b1 = *reinterpret_cast<const float4*>(&w[(size_t)(n0 + ar + 64) * NIN + kn + akc]);

#pragma unroll
        for (int kk = 0; kk < BK; ++kk) {
            const float4 av0 = *reinterpret_cast<const float4*>(&As[kk][ty4]);
            const float4 av1 = *reinterpret_cast<const float4*>(&As[kk][ty4 + 64]);
            const float4 bv0 = *reinterpret_cast<const float4*>(&Bs[kk][tx4]);
            const float4 bv1 = *reinterpret_cast<const float4*>(&Bs[kk][tx4 + 64]);
            const float ar_[8] = {av0.x, av0.y, av0.z, av0.w, av1.x, av1.y, av1.z, av1.w};
            const float br_[8] = {bv0.x, bv0.y, bv0.z, bv0.w, bv1.x, bv1.y, bv1.z, bv1.w};
#pragma unroll
            for (int i = 0; i < 8; ++i)
#pragma unroll
                for (int j = 0; j < 8; ++j)
                    acc[i][j] = fmaf(ar_[i], br_[j], acc[i][j]);
        }
    }

#pragma unroll
    for (int gi = 0; gi < 2; ++gi)
#pragma unroll
        for (int ii = 0; ii < 4; ++ii) {
            const int i = gi * 4 + ii;
            const int row = m0 + ty4 + ii + gi * 64;
            float* dst = &cur[(size_t)row * H + n0 + tx4];
            *reinterpret_cast<float4*>(dst)      = make_float4(acc[i][0], acc[i][1], acc[i][2], acc[i][3]);
            *reinterpret_cast<float4*>(dst + 64) = make_float4(acc[i][4], acc[i][5], acc[i][6], acc[i][7]);
        }
}

// ---------------------------------------------------------------------------
// Kernel 3 (FUSED TAIL): slots 0,1 (groups 0..31) = 64 scan blocks (XCD 0,1),
// R24 async-ring scan + R14 sentinel-spin P-prefetch. Slots 2..7 = 384
// persistent GEMM blocks (XCD 2..7, 2/CU, R19-dbuf) producing t in
// [T1S, 512) ascending, agent-scope store epilogue (R15-proven).
// ---------------------------------------------------------------------------
__global__ void fused_tail(const float* __restrict__ x,
                           const float* __restrict__ w,
                           float* __restrict__ io,
                           const float* __restrict__ wrecT) {
    // LDS union: scan needs ring 64KB + list 8.5KB + cnt (~74.3KB);
    // GEMM needs As/Bs 16.9KB. 2 blocks/CU at 74.3KB.
    __shared__ __align__(16) char smem[4 * 4 * 1024 * 4 + 2 * 1088 * 4 + 32];

    const int slot = blockIdx.x & 7;
    if (slot >= 2) {
        // --------------- persistent tail GEMM (R19-dbuf verbatim) ---------
        const int gp = blockIdx.x >> 3;
        const int pb = gp * 6 + (slot - 2);          // 0..383
        float* cur = io;

        float (*As)[LDSS] = reinterpret_cast<float (*)[LDSS]>(smem);
        float (*Bs)[LDSS] = reinterpret_cast<float (*)[LDSS]>(smem + BK * LDSS * sizeof(float));

        const int tid = threadIdx.x;
        const int tx = tid & 15, ty = tid >> 4;
        const int tx4 = tx * 4, ty4 = ty * 4;
        const int ar = tid >> 2;
        const int akc = (tid & 3) * 4;

        for (int wi = pb; wi < NI2; wi += PERS) {
            const int m0 = (M1T + (wi >> 3)) * BM;   // ascending timestep
            const int n0 = (wi & 7) * BN;

            float acc[8][8];
#pragma unroll
            for (int i = 0; i < 8; ++i)
#pragma unroll
                for (int j = 0; j < 8; ++j) acc[i][j] = 0.0f;

            float4 a0 = *reinterpret_cast<const float4*>(&x[(size_t)(m0 + ar) * NIN + akc]);
            float4 a1 = *reinterpret_cast<const float4*>(&x[(size_t)(m0 + ar + 64) * NIN + akc]);
            float4 b0 = *reinterpret_cast<const float4*>(&w[(size_t)(n0 + ar) * NIN + akc]);
            float4 b1 = *reinterpret_cast<const float4*>(&w[(size_t)(n0 + ar + 64) * NIN + akc]);

            for (int k0 = 0; k0 < NIN; k0 += BK) {
                __syncthreads();
                As[akc + 0][ar] = a0.x; As[akc + 1][ar] = a0.y; As[akc + 2][ar] = a0.z; As[akc + 3][ar] = a0.w;
                As[akc + 0][ar + 64] = a1.x; As[akc + 1][ar + 64] = a1.y; As[akc + 2][ar + 64] = a1.z; As[akc + 3][ar + 64] = a1.w;
                Bs[akc + 0][ar] = b0.x; Bs[akc + 1][ar] = b0.y; Bs[akc + 2][ar] = b0.z; Bs[akc + 3][ar] = b0.w;
                Bs[akc + 0][ar + 64] = b1.x; Bs[akc + 1][ar + 64] = b1.y; Bs[akc + 2][ar + 64] = b1.z; Bs[akc + 3][ar + 64] = b1.w;
                __syncthreads();

                const int kn = (k0 + BK < NIN) ? (k0 + BK) : 0;
                a0 = *reinterpret_cast<const float4*>(&x[(size_t)(m0 + ar) * NIN + kn + akc]);
                a1 = *reinterpret_cast<const float4*>(&x[(size_t)(m0 + ar + 64) * NIN + kn + akc]);
                b0 = *reinterpret_cast<const float4*>(&w[(size_t)(n0 + ar) * NIN + kn + akc]);
                b1 = *reinterpret_cast<const float4*>(&w[(size_t)(n0 + ar + 64) * NIN + kn + akc]);

#pragma unroll
                for (int kk = 0; kk < BK; ++kk) {
                    const float4 av0 = *reinterpret_cast<const float4*>(&As[kk][ty4]);
                    const float4 av1 = *reinterpret_cast<const float4*>(&As[kk][ty4 + 64]);
                    const float4 bv0 = *reinterpret_cast<const float4*>(&Bs[kk][tx4]);
                    const float4 bv1 = *reinterpret_cast<const float4*>(&Bs[kk][tx4 + 64]);
                    const float ar_[8] = {av0.x, av0.y, av0.z, av0.w, av1.x, av1.y, av1.z, av1.w};
                    const float br_[8] = {bv0.x, bv0.y, bv0.z, bv0.w, bv1.x, bv1.y, bv1.z, bv1.w};
#pragma unroll
                    for (int i = 0; i < 8; ++i)
#pragma unroll
                        for (int j = 0; j < 8; ++j)
                            acc[i][j] = fmaf(ar_[i], br_[j], acc[i][j]);
                }
            }

#pragma unroll
            for (int gi = 0; gi < 2; ++gi)
#pragma unroll
                for (int ii = 0; ii < 4; ++ii) {
                    const int i = gi * 4 + ii;
                    const int row = m0 + ty4 + ii + gi * 64;
                    float* dst = &cur[(size_t)row * H + n0 + tx4];
                    st_agent(dst + 0,  acc[i][0]); st_agent(dst + 1,  acc[i][1]);
                    st_agent(dst + 2,  acc[i][2]); st_agent(dst + 3,  acc[i][3]);
                    st_agent(dst + 64, acc[i][4]); st_agent(dst + 65, acc[i][5]);
                    st_agent(dst + 66, acc[i][6]); st_agent(dst + 67, acc[i][7]);
                }
        }
        return;
    }

    // --------------------------- scan path (R24 + sentinel spin) ----------
    if (blockIdx.x >= 256) return;
    const int b = (blockIdx.x >> 3) * 2 + slot;    // 0..63
    const int tid = threadIdx.x;
    const int wave = tid >> 6, lane = tid & 63;
    const int j0 = tid * 4;
    const int wq = wave * 256;

    float (*ring)[4][1024] = reinterpret_cast<float (*)[4][1024]>(smem);           // 64 KB
    int   (*list)[1088]    = reinterpret_cast<int (*)[1088]>(smem + 65536);        // 8704 B
    int   (*cnt)[4]        = reinterpret_cast<int (*)[4]>(smem + 65536 + 8704);    // 32 B

    float sv0 = 0.f, sv1 = 0.f, sv2 = 0.f, sv3 = 0.f;
    float si0 = 0.f, si1 = 0.f, si2 = 0.f, si3 = 0.f;
    float sb0 = 1.f, sb1 = 1.f, sb2 = 1.f, sb3 = 1.f;
    float sz0 = 0.f, sz1 = 0.f, sz2 = 0.f, sz3 = 0.f;
    int p = 0;
    int n_carry = 0;

    const float C_MEM = (float)(1e-3 * 100.0);
    const float C_SYN = (float)(1e-3 * 200.0);
    const float C_AD  = (float)(1e-3 * (1.0 / 800.0));
    const float BETA  = 1.8f;

    float* base = io + (size_t)b * H + j0;

    if (lane == 0) cnt[0][wave] = 0;
    asm volatile("s_waitcnt lgkmcnt(0)" ::: "memory");
    __builtin_amdgcn_s_barrier();

    f32x4 P0, P1, P2, P3, P4, P5, P6, P7;

// one prefetch register: 4 agent-scope scalar loads + sentinel check (R14)
#define LDP(REG, KK)                                                          \
      REG.x = ld_agent(pb_ + (size_t)(KK) * BH + 0);                          \
      REG.y = ld_agent(pb_ + (size_t)(KK) * BH + 1);                          \
      REG.z = ld_agent(pb_ + (size_t)(KK) * BH + 2);                          \
      REG.w = ld_agent(pb_ + (size_t)(KK) * BH + 3);                          \
      bad_ |= (unsigned)(__float_as_uint(REG.x) == SENTU);                    \
      bad_ |= (unsigned)(__float_as_uint(REG.y) == SENTU);                    \
      bad_ |= (unsigned)(__float_as_uint(REG.z) == SENTU);                    \
      bad_ |= (unsigned)(__float_as_uint(REG.w) == SENTU);

#define LOADP8_SPIN(PBASE)                                                    \
  { const float* pb_ = (PBASE);                                               \
    for (int tries_ = 0; tries_ < (1 << 14); ++tries_) {                      \
      unsigned bad_ = 0u;                                                     \
      LDP(P0, 0) LDP(P1, 1) LDP(P2, 2) LDP(P3, 3)                             \
      LDP(P4, 4) LDP(P5, 5) LDP(P6, 6) LDP(P7, 7)                             \
      if (__ballot(bad_ != 0u) == 0ull) break;                                \
      __builtin_amdgcn_s_sleep(8);                                            \
    } }

    LOADP8_SPIN(base);   // steps 0..7 produced by gemm_head -> immediate

// stage group G (4 rows) into ring slot G&3 (R24-proven)
#define STAGE(G)                                                              \
  { const int A0s_ = (G) << 2;                                                \
    _Pragma("unroll")                                                         \
    for (int rr_ = 0; rr_ < 4; ++rr_) {                                       \
      const int ps_ = A0s_ + rr_;                                             \
      int hs_ = lst[ps_];                                                     \
      hs_ = (ps_ < n) ? hs_ : 0;                                              \
      const float* gp_ = wrecT + (size_t)(unsigned)hs_ * H + wq + lane * 4;   \
      __builtin_amdgcn_global_load_lds(                                       \
          (const __attribute__((address_space(1))) unsigned int*)gp_,         \
          (__attribute__((address_space(3))) unsigned int*)&ring[(G) & 3][rr_][wq], \
          16, 0, 0);                                                          \
    } }

#define SCAN_STEP(T, CREG, PF)                                                \
  {                                                                           \
    const float cc0 = CREG.x, cc1 = CREG.y, cc2 = CREG.z, cc3 = CREG.w;       \
    const int n = __builtin_amdgcn_readfirstlane(n_carry);                    \
    const int NT = (n + 3) >> 2;                                              \
    const int* lst = &list[p][0];                                             \
    if (NT > 0) STAGE(0);                                                     \
    if (NT > 1) STAGE(1);                                                     \
    if (NT > 2) STAGE(2);                                                     \
    const float vd0 = sv0 + C_MEM * (0.0f - sv0 + si0);                       \
    const float vd1 = sv1 + C_MEM * (0.0f - sv1 + si1);                       \
    const float vd2 = sv2 + C_MEM * (0.0f - sv2 + si2);                       \
    const float vd3 = sv3 + C_MEM * (0.0f - sv3 + si3);                       \
    const float id0 = si0 - C_SYN * si0;                                      \
    const float id1 = si1 - C_SYN * si1;                                      \
    const float id2 = si2 - C_SYN * si2;                                      \
    const float id3 = si3 - C_SYN * si3;                                      \
    const float bd0 = sb0 + C_AD * (1.0f - sb0);                              \
    const float bd1 = sb1 + C_AD * (1.0f - sb1);                              \
    const float bd2 = sb2 + C_AD * (1.0f - sb2);                              \
    const float bd3 = sb3 + C_AD * (1.0f - sb3);                              \
    sz0 = ((vd0 - bd0) > 0.0f) ? 1.0f : 0.0f;                                 \
    sz1 = ((vd1 - bd1) > 0.0f) ? 1.0f : 0.0f;                                 \
    sz2 = ((vd2 - bd2) > 0.0f) ? 1.0f : 0.0f;                                 \
    sz3 = ((vd3 - bd3) > 0.0f) ? 1.0f : 0.0f;                                 \
    sv0 = (sz0 > 0.0f) ? 0.0f : vd0;                                          \
    sv1 = (sz1 > 0.0f) ? 0.0f : vd1;                                          \
    sv2 = (sz2 > 0.0f) ? 0.0f : vd2;                                          \
    sv3 = (sz3 > 0.0f) ? 0.0f : vd3;                                          \
    sb0 = (sz0 > 0.0f) ? (bd0 + BETA) : bd0;                                  \
    sb1 = (sz1 > 0.0f) ? (bd1 + BETA) : bd1;                                  \
    sb2 = (sz2 > 0.0f) ? (bd2 + BETA) : bd2;                                  \
    sb3 = (sz3 > 0.0f) ? (bd3 + BETA) : bd3;                                  \
    *reinterpret_cast<f32x4*>(base + (size_t)(T) * BH) =                      \
        (f32x4){sz0, sz1, sz2, sz3};                                          \
    const unsigned long long m0 = __ballot(sz0 > 0.0f);                       \
    const unsigned long long m1 = __ballot(sz1 > 0.0f);                       \
    const unsigned long long m2 = __ballot(sz2 > 0.0f);                       \
    const unsigned long long m3 = __ballot(sz3 > 0.0f);                       \
    unsigned pos = __builtin_amdgcn_mbcnt_hi((unsigned)(m0 >> 32),            \
                   __builtin_amdgcn_mbcnt_lo((unsigned)m0, 0u));              \
    pos = __builtin_amdgcn_mbcnt_hi((unsigned)(m1 >> 32),                     \
          __builtin_amdgcn_mbcnt_lo((unsigned)m1, pos));                      \
    pos = __builtin_amdgcn_mbcnt_hi((unsigned)(m2 >> 32),                     \
          __builtin_amdgcn_mbcnt_lo((unsigned)m2, pos));                      \
    pos = __builtin_amdgcn_mbcnt_hi((unsigned)(m3 >> 32),                     \
          __builtin_amdgcn_mbcnt_lo((unsigned)m3, pos));                      \
    if (lane == 0)                                                            \
      cnt[p ^ 1][wave] = __popcll(m0) + __popcll(m1) + __popcll(m2) + __popcll(m3); \
    asm volatile("s_waitcnt lgkmcnt(0)" ::: "memory");                        \
    __builtin_amdgcn_s_barrier();                                             \
    const int4 nc = *reinterpret_cast<const int4*>(&cnt[p ^ 1][0]);           \
    n_carry = nc.x + nc.y + nc.z + nc.w;                                      \
    const int woff = (wave > 0 ? nc.x : 0) + (wave > 1 ? nc.y : 0) +          \
                     (wave > 2 ? nc.z : 0);                                   \
    int* dst = &list[p ^ 1][woff];                                            \
    if (sz0 > 0.0f) dst[pos++] = j0 + 0;                                      \
    if (sz1 > 0.0f) dst[pos++] = j0 + 1;                                      \
    if (sz2 > 0.0f) dst[pos++] = j0 + 2;                                      \
    if (sz3 > 0.0f) dst[pos++] = j0 + 3;                                      \
    asm volatile("s_waitcnt lgkmcnt(0)" ::: "memory");                        \
    __builtin_amdgcn_s_barrier();                                             \
    float r0 = 0.f, r1 = 0.f, r2 = 0.f, r3 = 0.f;                             \
    {                                                                         \
      for (int g = 0; g < NT; ++g) {                                          \
        const int rem = NT - 1 - g;                                           \
        if (rem >= 2)      { asm volatile("s_waitcnt vmcnt(8)" ::: "memory"); } \
        else if (rem == 1) { asm volatile("s_waitcnt vmcnt(4)" ::: "memory"); } \
        else               { asm volatile("s_waitcnt vmcnt(0)" ::: "memory"); } \
        const int sl = g & 3;                                                 \
        const f32x4 w0 = *reinterpret_cast<const f32x4*>(&ring[sl][0][j0]);   \
        const f32x4 w1 = *reinterpret_cast<const f32x4*>(&ring[sl][1][j0]);   \
        const f32x4 w2 = *reinterpret_cast<const f32x4*>(&ring[sl][2][j0]);   \
        const f32x4 w3 = *reinterpret_cast<const f32x4*>(&ring[sl][3][j0]);   \
        const int gb = g << 2;                                                \
        if (gb + 4 <= n) {                                                    \
          r0 += w0.x; r1 += w0.y; r2 += w0.z; r3 += w0.w;                     \
          r0 += w1.x; r1 += w1.y; r2 += w1.z; r3 += w1.w;                     \
          r0 += w2.x; r1 += w2.y; r2 += w2.z; r3 += w2.w;                     \
          r0 += w3.x; r1 += w3.y; r2 += w3.z; r3 += w3.w;                     \
        } else {                                                              \
          const float ma_ = (gb + 0 < n) ? 1.0f : 0.0f;                       \
          r0 = fmaf(ma_, w0.x, r0); r1 = fmaf(ma_, w0.y, r1);                 \
          r2 = fmaf(ma_, w0.z, r2); r3 = fmaf(ma_, w0.w, r3);                 \
          const float mb_ = (gb + 1 < n) ? 1.0f : 0.0f;                       \
          r0 = fmaf(mb_, w1.x, r0); r1 = fmaf(mb_, w1.y, r1);                 \
          r2 = fmaf(mb_, w1.z, r2); r3 = fmaf(mb_, w1.w, r3);                 \
          const float mc_ = (gb + 2 < n) ? 1.0f : 0.0f;                       \
          r0 = fmaf(mc_, w2.x, r0); r1 = fmaf(mc_, w2.y, r1);                 \
          r2 = fmaf(mc_, w2.z, r2); r3 = fmaf(mc_, w2.w, r3);                 \
          const float md_ = (gb + 3 < n) ? 1.0f : 0.0f;                       \
          r0 = fmaf(md_, w3.x, r0); r1 = fmaf(md_, w3.y, r1);                 \
          r2 = fmaf(md_, w3.z, r2); r3 = fmaf(md_, w3.w, r3);                 \
        }                                                                     \
        if (g + 3 < NT) STAGE(g + 3);                                         \
      }                                                                       \
    }                                                                         \
    if (PF) {                                                                 \
      if ((T) + 1 < T_STEPS) {                                                \
        LOADP8_SPIN(base + (size_t)((T) + 1) * BH);                           \
      }                                                                       \
    }                                                                         \
    si0 = (id0 + cc0) + r0;                                                   \
    si1 = (id1 + cc1) + r1;                                                   \
    si2 = (id2 + cc2) + r2;                                                   \
    si3 = (id3 + cc3) + r3;                                                   \
    p ^= 1;                                                                   \
  }

    for (int t = 0; t < T_STEPS; t += 8) {
        SCAN_STEP(t,     P0, 0);
        SCAN_STEP(t + 1, P1, 0);
        SCAN_STEP(t + 2, P2, 0);
        SCAN_STEP(t + 3, P3, 0);
        SCAN_STEP(t + 4, P4, 0);
        SCAN_STEP(t + 5, P5, 0);
        SCAN_STEP(t + 6, P6, 0);
        SCAN_STEP(t + 7, P7, 1);
    }
#undef SCAN_STEP
#undef STAGE
#undef LOADP8_SPIN
#undef LDP

    float* fo = io + (size_t)T_STEPS * BH + (size_t)b * H + j0;
    *reinterpret_cast<float4*>(fo)          = make_float4(sz0, sz1, sz2, sz3);
    *reinterpret_cast<float4*>(fo + BH)     = make_float4(sv0, sv1, sv2, sv3);
    *reinterpret_cast<float4*>(fo + 2 * BH) = make_float4(si0, si1, si2, si3);
    *reinterpret_cast<float4*>(fo + 3 * BH) = make_float4(sb0, sb1, sb2, sb3);
}

// ---------------------------------------------------------------------------
extern "C" void kernel_launch(void* const* d_in, const int* in_sizes, int n_in,
                              void* d_out, int out_size, void* d_ws, size_t ws_size,
                              hipStream_t stream) {
    const float* x     = (const float*)d_in[0];
    const float* w_in  = (const float*)d_in[1];
    const float* w_rec = (const float*)d_in[2];
    float* out   = (float*)d_out;
    float* wrecT = (float*)d_ws;

    // arm the sentinel only over the tail region (t >= T1S)
    hipMemsetAsync(out + (size_t)T1S * BH, 0x7F,
                   (size_t)(T_STEPS - T1S) * BH * sizeof(float), stream);
    transpose1024<<<dim3(H / 32, H / 32), dim3(32, 8), 0, stream>>>(w_rec, wrecT);
    gemm_head<<<dim3(H / BN, (T1S * BATCH) / BM), 256, 0, stream>>>(x, w_in, out);
    fused_tail<<<dim3(64 * 8), 256, 0, stream>>>(x, w_in, out, wrecT);
}